// Round 5
// baseline (702.635 us; speedup 1.0000x reference)
//
#include <hip/hip_runtime.h>
#include <math.h>

#define NN 50000
#define NE 1600000
#define H  64

#define SHIFT 7                 // 128 nodes per bucket
#define NPBKT 128
#define NB    391               // ceil(50000/128)
#define CHUNK 4096
#define NCH   391               // ceil(NE/CHUNK)

typedef __attribute__((ext_vector_type(8))) short s16v8;   // 8 bf16
typedef __attribute__((ext_vector_type(4))) float f32v4;   // MFMA acc
typedef unsigned short u16;
typedef unsigned int   u32;

__device__ __forceinline__ u16 f2bf(float x) {             // RNE f32->bf16
    union { float f; unsigned u; } v; v.f = x;
    unsigned r = v.u + 0x7FFF + ((v.u >> 16) & 1);
    return (u16)(r >> 16);
}
__device__ __forceinline__ float bf2f(u16 h) {
    union { float f; unsigned u; } v; v.u = ((unsigned)h) << 16; return v.f;
}

// ============ CSR build, bucketized ============
__global__ __launch_bounds__(256) void hist_kernel(const int* __restrict__ dst,
                                                   int* __restrict__ chunkhist) {
    __shared__ int h[NB];
    const int c = blockIdx.x;
    for (int b = threadIdx.x; b < NB; b += 256) h[b] = 0;
    __syncthreads();
    const int e0 = c * CHUNK, e1 = min(NE, e0 + CHUNK);
    for (int e = e0 + threadIdx.x; e < e1; e += 256)
        atomicAdd(&h[dst[e] >> SHIFT], 1);
    __syncthreads();
    for (int b = threadIdx.x; b < NB; b += 256)
        chunkhist[c * NB + b] = h[b];
}

__global__ __launch_bounds__(512) void cscan_kernel(int* __restrict__ chunkhist,
                                                    int* __restrict__ bbase) {
    __shared__ int s[512];
    const int t = threadIdx.x;
    int tot = 0;
    if (t < NB)
        for (int c = 0; c < NCH; ++c) tot += chunkhist[c * NB + t];
    s[t] = (t < NB) ? tot : 0;
    __syncthreads();
    for (int d = 1; d < 512; d <<= 1) {
        int v = (t >= d) ? s[t - d] : 0;
        __syncthreads();
        s[t] += v;
        __syncthreads();
    }
    if (t < NB) {
        int base = s[t] - tot;             // exclusive
        bbase[t] = base;
        if (t == NB - 1) bbase[NB] = s[t];
        int run = base;
        for (int c = 0; c < NCH; ++c) {
            int tmp = chunkhist[c * NB + t];
            chunkhist[c * NB + t] = run;
            run += tmp;
        }
    }
}

__global__ __launch_bounds__(256) void scat_kernel(const int* __restrict__ src,
                                                   const int* __restrict__ dst,
                                                   const int* __restrict__ chunkhist,
                                                   u32* __restrict__ bin) {
    __shared__ int base[NB];
    __shared__ int cur[NB];
    const int c = blockIdx.x;
    for (int b = threadIdx.x; b < NB; b += 256) {
        base[b] = chunkhist[c * NB + b];
        cur[b] = 0;
    }
    __syncthreads();
    const int e0 = c * CHUNK, e1 = min(NE, e0 + CHUNK);
    for (int e = e0 + threadIdx.x; e < e1; e += 256) {
        int d = dst[e];
        int b = d >> SHIFT;
        int p = atomicAdd(&cur[b], 1);
        bin[base[b] + p] = (u32)src[e] | ((u32)(d & (NPBKT - 1)) << 16);
    }
}

__global__ __launch_bounds__(256) void binB_kernel(const u32* __restrict__ bin,
                                                   const int* __restrict__ bbase,
                                                   int* __restrict__ off,
                                                   u16* __restrict__ csr) {
    __shared__ int deg[NPBKT];
    __shared__ int sc[NPBKT];
    __shared__ int cur[NPBKT];
    const int b = blockIdx.x, t = threadIdx.x;
    const int seg0 = bbase[b], seg1 = bbase[b + 1];
    if (t < NPBKT) { deg[t] = 0; cur[t] = 0; }
    __syncthreads();
    for (int i = seg0 + t; i < seg1; i += 256)
        atomicAdd(&deg[(bin[i] >> 16) & (NPBKT - 1)], 1);
    __syncthreads();
    if (t < NPBKT) sc[t] = deg[t];
    __syncthreads();
    for (int d = 1; d < NPBKT; d <<= 1) {
        int v = 0;
        if (t < NPBKT && t >= d) v = sc[t - d];
        __syncthreads();
        if (t < NPBKT) sc[t] += v;
        __syncthreads();
    }
    if (t < NPBKT) {
        sc[t] -= deg[t];
        int node = b * NPBKT + t;
        if (node < NN) off[node] = seg0 + sc[t];
        if (b == 0 && t == 0) off[NN] = NE;
    }
    __syncthreads();
    for (int i = seg0 + t; i < seg1; i += 256) {
        u32 e = bin[i];
        int n = (e >> 16) & (NPBKT - 1);
        int p = atomicAdd(&cur[n], 1);
        csr[seg0 + sc[n] + p] = (u16)(e & 0xFFFF);
    }
}

// ============ weight prep: transpose + split into bf16 hi/lo planes ======
__global__ __launch_bounds__(256) void prep_kernel(const float* __restrict__ W1,
        const float* __restrict__ W2, const float* __restrict__ W3,
        u16* __restrict__ wt) {
    int idx = blockIdx.x * 256 + threadIdx.x;
    if (idx >= 2 * 40960) return;
    int b = idx / 40960, r = idx - b * 40960;
    float v; int hioff, losz;
    if (r < 16384) {
        int col = r >> 7, k = r & 127;
        v = W1[b * 24576 + k * 128 + col];
        hioff = b * 81920 + r; losz = 16384;
    } else if (r < 32768) {
        int rr = r - 16384; int col = rr >> 7, k = rr & 127;
        v = W2[b * 16384 + k * 128 + col];
        hioff = b * 81920 + 32768 + rr; losz = 16384;
    } else {
        int rr = r - 32768; int col = rr >> 7, k = rr & 127;
        v = W3[b * 8192 + k * 64 + col];
        hioff = b * 81920 + 65536 + rr; losz = 8192;
    }
    u16 hi = f2bf(v);
    u16 lo = f2bf(v - bf2f(hi));
    wt[hioff] = hi; wt[hioff + losz] = lo;
}

// ============ grep partials (no atomics) ============
__global__ __launch_bounds__(256) void grep_kernel(const float* __restrict__ h,
                                                   float* __restrict__ partial) {
    const int c  = threadIdx.x & 63;
    const int rl = threadIdx.x >> 6;
    float acc = 0.f;
    for (int r = blockIdx.x * 4 + rl; r < NN; r += gridDim.x * 4)
        acc += h[r * H + c];
    __shared__ float s[4][64];
    s[rl][c] = acc;
    __syncthreads();
    if (threadIdx.x < 64)
        partial[blockIdx.x * 64 + threadIdx.x] =
            s[0][threadIdx.x] + s[1][threadIdx.x] +
            s[2][threadIdx.x] + s[3][threadIdx.x];
}

// ============ b1e: reduce partials + fold grep term into layer-1 bias ====
__global__ __launch_bounds__(128) void b1e_kernel(const float* __restrict__ partial,
        const float* __restrict__ W1, const float* __restrict__ b1,
        float* __restrict__ b1e) {
    __shared__ float g[64];
    const int t = threadIdx.x;
    if (t < 64) {
        float s = 0.f;
        for (int i = 0; i < 256; ++i) s += partial[i * 64 + t];
        g[t] = s;
    }
    __syncthreads();
    float s = b1[t];
    for (int k = 0; k < 64; ++k)
        s = fmaf(g[k], W1[(128 + k) * 128 + t], s);
    b1e[t] = s;
}

// ============ gather: agg[n] = sum hidden[src_e] ============
__global__ __launch_bounds__(256) void gather_kernel(const float* __restrict__ h,
                                                     const u16* __restrict__ csr,
                                                     const int* __restrict__ off,
                                                     float* __restrict__ agg) {
    const int wid = blockIdx.x * 4 + (threadIdx.x >> 6);
    if (wid >= NN) return;
    const int lane = threadIdx.x & 63;
    const int g = lane >> 4, sub = lane & 15;
    const int beg = off[wid], end = off[wid + 1];
    float4 acc = {0.f, 0.f, 0.f, 0.f};
    for (int e = beg + g; e < end; e += 4) {
        int s = csr[e];
        float4 v = *(const float4*)&h[(size_t)s * H + sub * 4];
        acc.x += v.x; acc.y += v.y; acc.z += v.z; acc.w += v.w;
    }
#pragma unroll
    for (int o = 16; o <= 32; o <<= 1) {
        acc.x += __shfl_xor(acc.x, o);
        acc.y += __shfl_xor(acc.y, o);
        acc.z += __shfl_xor(acc.z, o);
        acc.w += __shfl_xor(acc.w, o);
    }
    if (g == 0)
        *(float4*)&agg[(size_t)wid * H + sub * 4] = acc;
}

// ============ fused MFMA MLP (split-bf16), 32 nodes/block, 4 waves ========
// wave w: rows (w>>1)*16 .. +15 ; output-column tiles ntbase=(w&1)*4 .. +3.
// LDS: single reused 32x128 hi/lo activation buffer (16 KB).
__global__ __launch_bounds__(256) void mlp_mfma(
    const float* __restrict__ agg, const float* __restrict__ hin,
    const float* __restrict__ b1e, const u16* __restrict__ wt,
    const float* __restrict__ b2, const float* __restrict__ b3,
    float* __restrict__ out)
{
    __shared__ u16 hhi[32 * 128], hlo[32 * 128];
    const int t = threadIdx.x;
    const int wl = t >> 6;
    const int lane = t & 63;
    const int li = lane & 15, g = lane >> 4;
    const int n0 = blockIdx.x * 32;
    const int rowbase = (wl >> 1) * 16;          // 0 or 16
    const int ntbase  = (wl & 1) * 4;            // tiles 0-3 or 4-7
    const int arow = min(n0 + rowbase + li, NN - 1);

    const u16* w1hi = wt;
    const u16* w1lo = wt + 16384;
    const u16* w2hi = wt + 32768;
    const u16* w2lo = wt + 49152;
    const u16* w3hi = wt + 65536;
    const u16* w3lo = wt + 73728;

    // ---- L1: x=[agg|hidden] (192->128, grep folded into b1e) ----
    f32v4 acc[4];
#pragma unroll
    for (int i = 0; i < 4; ++i) acc[i] = (f32v4){0.f, 0.f, 0.f, 0.f};
#pragma unroll
    for (int ks = 0; ks < 4; ++ks) {
        const float* sp = ((ks < 2) ? agg : hin) + (size_t)arow * 64 + (ks & 1) * 32 + g * 8;
        float4 u0 = *(const float4*)sp;
        float4 u1 = *(const float4*)(sp + 4);
        float f[8] = {u0.x, u0.y, u0.z, u0.w, u1.x, u1.y, u1.z, u1.w};
        s16v8 ahi, alo;
#pragma unroll
        for (int j = 0; j < 8; ++j) {
            u16 hb = f2bf(f[j]);
            ahi[j] = (short)hb;
            alo[j] = (short)f2bf(f[j] - bf2f(hb));
        }
        const int kw = ks * 32 + g * 8;
#pragma unroll
        for (int nt = 0; nt < 4; ++nt) {
            const int c = (ntbase + nt) * 16 + li;
            s16v8 bhi = *(const s16v8*)(w1hi + c * 128 + kw);
            s16v8 blo = *(const s16v8*)(w1lo + c * 128 + kw);
            acc[nt] = __builtin_amdgcn_mfma_f32_16x16x32_bf16(ahi, bhi, acc[nt], 0, 0, 0);
            acc[nt] = __builtin_amdgcn_mfma_f32_16x16x32_bf16(ahi, blo, acc[nt], 0, 0, 0);
            acc[nt] = __builtin_amdgcn_mfma_f32_16x16x32_bf16(alo, bhi, acc[nt], 0, 0, 0);
        }
    }
#pragma unroll
    for (int nt = 0; nt < 4; ++nt) {
        const int c = (ntbase + nt) * 16 + li;
        const float bb = b1e[c];
#pragma unroll
        for (int r = 0; r < 4; ++r) {
            float hv = fmaxf(acc[nt][r] + bb, 0.f);
            u16 hb = f2bf(hv);
            u16 lb = f2bf(hv - bf2f(hb));
            const int row = rowbase + 4 * g + r;
            const int addr = row * 128 + ((((c >> 3) ^ (row & 7)) << 3) | (c & 7));
            hhi[addr] = hb; hlo[addr] = lb;
        }
    }
    __syncthreads();

    // ---- L2: 128->128 ----
    f32v4 acc2[4];
#pragma unroll
    for (int i = 0; i < 4; ++i) acc2[i] = (f32v4){0.f, 0.f, 0.f, 0.f};
#pragma unroll
    for (int ks = 0; ks < 4; ++ks) {
        const int ablk = (((ks * 4 + g) ^ (li & 7)) << 3);
        s16v8 ahi = *(const s16v8*)&hhi[(rowbase + li) * 128 + ablk];
        s16v8 alo = *(const s16v8*)&hlo[(rowbase + li) * 128 + ablk];
        const int kw = ks * 32 + g * 8;
#pragma unroll
        for (int nt = 0; nt < 4; ++nt) {
            const int c = (ntbase + nt) * 16 + li;
            s16v8 bhi = *(const s16v8*)(w2hi + c * 128 + kw);
            s16v8 blo = *(const s16v8*)(w2lo + c * 128 + kw);
            acc2[nt] = __builtin_amdgcn_mfma_f32_16x16x32_bf16(ahi, bhi, acc2[nt], 0, 0, 0);
            acc2[nt] = __builtin_amdgcn_mfma_f32_16x16x32_bf16(ahi, blo, acc2[nt], 0, 0, 0);
            acc2[nt] = __builtin_amdgcn_mfma_f32_16x16x32_bf16(alo, bhi, acc2[nt], 0, 0, 0);
        }
    }
    __syncthreads();                             // all h1 reads done
#pragma unroll
    for (int nt = 0; nt < 4; ++nt) {
        const int c = (ntbase + nt) * 16 + li;
        const float bb = b2[c];
#pragma unroll
        for (int r = 0; r < 4; ++r) {
            float hv = fmaxf(acc2[nt][r] + bb, 0.f);
            u16 hb = f2bf(hv);
            u16 lb = f2bf(hv - bf2f(hb));
            const int row = rowbase + 4 * g + r;
            const int addr = row * 128 + ((((c >> 3) ^ (row & 7)) << 3) | (c & 7));
            hhi[addr] = hb; hlo[addr] = lb;      // overwrite h1 with h2
        }
    }
    __syncthreads();

    // ---- L3: 128->64 + row L2 norm (wave pair duplicates; even wave stores)
    f32v4 acc3[4];
#pragma unroll
    for (int i = 0; i < 4; ++i) acc3[i] = (f32v4){0.f, 0.f, 0.f, 0.f};
#pragma unroll
    for (int ks = 0; ks < 4; ++ks) {
        const int ablk = (((ks * 4 + g) ^ (li & 7)) << 3);
        s16v8 ahi = *(const s16v8*)&hhi[(rowbase + li) * 128 + ablk];
        s16v8 alo = *(const s16v8*)&hlo[(rowbase + li) * 128 + ablk];
        const int kw = ks * 32 + g * 8;
#pragma unroll
        for (int nt = 0; nt < 4; ++nt) {
            const int c = nt * 16 + li;
            s16v8 bhi = *(const s16v8*)(w3hi + c * 128 + kw);
            s16v8 blo = *(const s16v8*)(w3lo + c * 128 + kw);
            acc3[nt] = __builtin_amdgcn_mfma_f32_16x16x32_bf16(ahi, bhi, acc3[nt], 0, 0, 0);
            acc3[nt] = __builtin_amdgcn_mfma_f32_16x16x32_bf16(ahi, blo, acc3[nt], 0, 0, 0);
            acc3[nt] = __builtin_amdgcn_mfma_f32_16x16x32_bf16(alo, bhi, acc3[nt], 0, 0, 0);
        }
    }
    if ((wl & 1) == 0) {
        float b3c[4];
#pragma unroll
        for (int nt = 0; nt < 4; ++nt) b3c[nt] = b3[nt * 16 + li];
#pragma unroll
        for (int r = 0; r < 4; ++r) {
            float v[4]; float ss = 0.f;
#pragma unroll
            for (int nt = 0; nt < 4; ++nt) {
                v[nt] = acc3[nt][r] + b3c[nt];
                ss = fmaf(v[nt], v[nt], ss);
            }
#pragma unroll
            for (int o = 1; o <= 8; o <<= 1) ss += __shfl_xor(ss, o);
            const float inv = rsqrtf(ss);
            const int node = n0 + rowbase + 4 * g + r;
            if (node < NN) {
#pragma unroll
                for (int nt = 0; nt < 4; ++nt)
                    out[(size_t)node * 64 + nt * 16 + li] = v[nt] * inv;
            }
        }
    }
}

// -------------------------------------------------------------------------
extern "C" void kernel_launch(void* const* d_in, const int* in_sizes, int n_in,
                              void* d_out, int out_size, void* d_ws, size_t ws_size,
                              hipStream_t stream) {
    const float* hidden = (const float*)d_in[0];
    const int*   src    = (const int*)d_in[1];
    const int*   dst    = (const int*)d_in[2];
    const float* W1f    = (const float*)d_in[3];
    const float* b1f    = (const float*)d_in[4];
    const float* W2f    = (const float*)d_in[5];
    const float* b2f    = (const float*)d_in[6];
    const float* W3f    = (const float*)d_in[7];
    const float* b3f    = (const float*)d_in[8];

    float* agg     = (float*)d_ws;                        // NN*H
    float* b1e     = agg + (size_t)NN * H;                // 128
    float* partial = b1e + 128;                           // 256*64
    float* hA      = partial + 256 * 64;                  // NN*H
    int*   bbase   = (int*)(hA + (size_t)NN * H);         // NB+1
    int*   off     = bbase + (NB + 1);                    // NN+1
    int*   chist   = off + (NN + 1);                      // NCH*NB
    u32*   bin     = (u32*)(chist + NCH * NB);            // NE
    u16*   csr     = (u16*)(bin + NE);                    // NE
    u16*   wt      = (u16*)(((uintptr_t)(csr + NE) + 255) & ~(uintptr_t)255);

    // ---- one-time per call: bucketized CSR + weight planes ----
    hist_kernel<<<NCH, 256, 0, stream>>>(dst, chist);
    cscan_kernel<<<1, 512, 0, stream>>>(chist, bbase);
    scat_kernel<<<NCH, 256, 0, stream>>>(src, dst, chist, bin);
    binB_kernel<<<NB, 256, 0, stream>>>(bin, bbase, off, csr);
    prep_kernel<<<(2 * 40960 + 255) / 256, 256, 0, stream>>>(W1f, W2f, W3f, wt);

    const float* hin = hidden;
    float* houts[4] = { hA, (float*)d_out, hA, (float*)d_out };

    for (int it = 0; it < 4; ++it) {
        const int blk = it >> 1;
        grep_kernel<<<256, 256, 0, stream>>>(hin, partial);
        b1e_kernel<<<1, 128, 0, stream>>>(partial, W1f + blk * 24576, b1f + blk * 128, b1e);
        gather_kernel<<<(NN + 3) / 4, 256, 0, stream>>>(hin, csr, off, agg);
        mlp_mfma<<<(NN + 31) / 32, 256, 0, stream>>>(agg, hin, b1e, wt + blk * 81920,
            b2f + blk * 128, b3f + blk * 64, houts[it]);
        hin = houts[it];
    }
}

// Round 6
// 515.947 us; speedup vs baseline: 1.3618x; 1.3618x over previous
//
#include <hip/hip_runtime.h>
#include <math.h>

#define NN 50000
#define NE 1600000
#define H  64

#define SHIFT 7                 // 128 nodes per bucket
#define NPBKT 128
#define NB    391               // ceil(50000/128)
#define CHUNK 4096
#define NCH   391               // ceil(NE/CHUNK)

typedef __attribute__((ext_vector_type(8))) short s16v8;   // 8 bf16
typedef __attribute__((ext_vector_type(4))) float f32v4;   // MFMA acc
typedef unsigned short u16;
typedef unsigned int   u32;

__device__ __forceinline__ u16 f2bf(float x) {             // RNE f32->bf16
    union { float f; unsigned u; } v; v.f = x;
    unsigned r = v.u + 0x7FFF + ((v.u >> 16) & 1);
    return (u16)(r >> 16);
}
__device__ __forceinline__ float bf2f(u16 h) {
    union { float f; unsigned u; } v; v.u = ((unsigned)h) << 16; return v.f;
}

// ============ CSR build, bucketized ============
__global__ __launch_bounds__(256) void hist_kernel(const int* __restrict__ dst,
                                                   int* __restrict__ chunkhist) {
    __shared__ int h[NB];
    const int c = blockIdx.x;
    for (int b = threadIdx.x; b < NB; b += 256) h[b] = 0;
    __syncthreads();
    const int e0 = c * CHUNK, e1 = min(NE, e0 + CHUNK);
    for (int e = e0 + threadIdx.x; e < e1; e += 256)
        atomicAdd(&h[dst[e] >> SHIFT], 1);
    __syncthreads();
    for (int b = threadIdx.x; b < NB; b += 256)
        chunkhist[c * NB + b] = h[b];
}

__global__ __launch_bounds__(512) void cscan_kernel(int* __restrict__ chunkhist,
                                                    int* __restrict__ bbase) {
    __shared__ int s[512];
    const int t = threadIdx.x;
    int tot = 0;
    if (t < NB)
        for (int c = 0; c < NCH; ++c) tot += chunkhist[c * NB + t];
    s[t] = (t < NB) ? tot : 0;
    __syncthreads();
    for (int d = 1; d < 512; d <<= 1) {
        int v = (t >= d) ? s[t - d] : 0;
        __syncthreads();
        s[t] += v;
        __syncthreads();
    }
    if (t < NB) {
        int base = s[t] - tot;             // exclusive
        bbase[t] = base;
        if (t == NB - 1) bbase[NB] = s[t];
        int run = base;
        for (int c = 0; c < NCH; ++c) {
            int tmp = chunkhist[c * NB + t];
            chunkhist[c * NB + t] = run;
            run += tmp;
        }
    }
}

__global__ __launch_bounds__(256) void scat_kernel(const int* __restrict__ src,
                                                   const int* __restrict__ dst,
                                                   const int* __restrict__ chunkhist,
                                                   u32* __restrict__ bin) {
    __shared__ int base[NB];
    __shared__ int cur[NB];
    const int c = blockIdx.x;
    for (int b = threadIdx.x; b < NB; b += 256) {
        base[b] = chunkhist[c * NB + b];
        cur[b] = 0;
    }
    __syncthreads();
    const int e0 = c * CHUNK, e1 = min(NE, e0 + CHUNK);
    for (int e = e0 + threadIdx.x; e < e1; e += 256) {
        int d = dst[e];
        int b = d >> SHIFT;
        int p = atomicAdd(&cur[b], 1);
        bin[base[b] + p] = (u32)src[e] | ((u32)(d & (NPBKT - 1)) << 16);
    }
}

__global__ __launch_bounds__(256) void binB_kernel(const u32* __restrict__ bin,
                                                   const int* __restrict__ bbase,
                                                   int* __restrict__ off,
                                                   u16* __restrict__ csr) {
    __shared__ int deg[NPBKT];
    __shared__ int sc[NPBKT];
    __shared__ int cur[NPBKT];
    const int b = blockIdx.x, t = threadIdx.x;
    const int seg0 = bbase[b], seg1 = bbase[b + 1];
    if (t < NPBKT) { deg[t] = 0; cur[t] = 0; }
    __syncthreads();
    for (int i = seg0 + t; i < seg1; i += 256)
        atomicAdd(&deg[(bin[i] >> 16) & (NPBKT - 1)], 1);
    __syncthreads();
    if (t < NPBKT) sc[t] = deg[t];
    __syncthreads();
    for (int d = 1; d < NPBKT; d <<= 1) {
        int v = 0;
        if (t < NPBKT && t >= d) v = sc[t - d];
        __syncthreads();
        if (t < NPBKT) sc[t] += v;
        __syncthreads();
    }
    if (t < NPBKT) {
        sc[t] -= deg[t];
        int node = b * NPBKT + t;
        if (node < NN) off[node] = seg0 + sc[t];
        if (b == 0 && t == 0) off[NN] = NE;
    }
    __syncthreads();
    for (int i = seg0 + t; i < seg1; i += 256) {
        u32 e = bin[i];
        int n = (e >> 16) & (NPBKT - 1);
        int p = atomicAdd(&cur[n], 1);
        csr[seg0 + sc[n] + p] = (u16)(e & 0xFFFF);
    }
}

// ============ weight prep: transpose + split into bf16 hi/lo planes ======
__global__ __launch_bounds__(256) void prep_kernel(const float* __restrict__ W1,
        const float* __restrict__ W2, const float* __restrict__ W3,
        u16* __restrict__ wt) {
    int idx = blockIdx.x * 256 + threadIdx.x;
    if (idx >= 2 * 40960) return;
    int b = idx / 40960, r = idx - b * 40960;
    float v; int hioff, losz;
    if (r < 16384) {
        int col = r >> 7, k = r & 127;
        v = W1[b * 24576 + k * 128 + col];
        hioff = b * 81920 + r; losz = 16384;
    } else if (r < 32768) {
        int rr = r - 16384; int col = rr >> 7, k = rr & 127;
        v = W2[b * 16384 + k * 128 + col];
        hioff = b * 81920 + 32768 + rr; losz = 16384;
    } else {
        int rr = r - 32768; int col = rr >> 7, k = rr & 127;
        v = W3[b * 8192 + k * 64 + col];
        hioff = b * 81920 + 65536 + rr; losz = 8192;
    }
    u16 hi = f2bf(v);
    u16 lo = f2bf(v - bf2f(hi));
    wt[hioff] = hi; wt[hioff + losz] = lo;
}

// ============ grep partials (no atomics) ============
__global__ __launch_bounds__(256) void grep_kernel(const float* __restrict__ h,
                                                   float* __restrict__ partial) {
    const int c  = threadIdx.x & 63;
    const int rl = threadIdx.x >> 6;
    float acc = 0.f;
    for (int r = blockIdx.x * 4 + rl; r < NN; r += gridDim.x * 4)
        acc += h[r * H + c];
    __shared__ float s[4][64];
    s[rl][c] = acc;
    __syncthreads();
    if (threadIdx.x < 64)
        partial[blockIdx.x * 64 + threadIdx.x] =
            s[0][threadIdx.x] + s[1][threadIdx.x] +
            s[2][threadIdx.x] + s[3][threadIdx.x];
}

// ============ b1e: reduce partials + fold grep term into layer-1 bias ====
__global__ __launch_bounds__(128) void b1e_kernel(const float* __restrict__ partial,
        const float* __restrict__ W1, const float* __restrict__ b1,
        float* __restrict__ b1e) {
    __shared__ float g[64];
    const int t = threadIdx.x;
    if (t < 64) {
        float s = 0.f;
        for (int i = 0; i < 256; ++i) s += partial[i * 64 + t];
        g[t] = s;
    }
    __syncthreads();
    float s = b1[t];
    for (int k = 0; k < 64; ++k)
        s = fmaf(g[k], W1[(128 + k) * 128 + t], s);
    b1e[t] = s;
}

// ============ gather: agg[n] = sum hidden[src_e] ============
__global__ __launch_bounds__(256) void gather_kernel(const float* __restrict__ h,
                                                     const u16* __restrict__ csr,
                                                     const int* __restrict__ off,
                                                     float* __restrict__ agg) {
    const int wid = blockIdx.x * 4 + (threadIdx.x >> 6);
    if (wid >= NN) return;
    const int lane = threadIdx.x & 63;
    const int g = lane >> 4, sub = lane & 15;
    const int beg = off[wid], end = off[wid + 1];
    float4 acc = {0.f, 0.f, 0.f, 0.f};
    for (int e = beg + g; e < end; e += 4) {
        int s = csr[e];
        float4 v = *(const float4*)&h[(size_t)s * H + sub * 4];
        acc.x += v.x; acc.y += v.y; acc.z += v.z; acc.w += v.w;
    }
#pragma unroll
    for (int o = 16; o <= 32; o <<= 1) {
        acc.x += __shfl_xor(acc.x, o);
        acc.y += __shfl_xor(acc.y, o);
        acc.z += __shfl_xor(acc.z, o);
        acc.w += __shfl_xor(acc.w, o);
    }
    if (g == 0)
        *(float4*)&agg[(size_t)wid * H + sub * 4] = acc;
}

// ============ fused MFMA MLP: B-hoisted-in-registers version ============
// 64 nodes/block, 4 waves. Wave wl owns col-tiles {2wl, 2wl+1} (L1/L2) and
// col-tile wl (L3), over ALL 64 rows. B-frags loaded once per layer into
// registers; A-frags stream from swizzled LDS hi/lo planes.
__device__ __forceinline__ int swz(int row, int cb) {      // u16 index
    return row * 128 + (((cb ^ (row & 7)) << 3));
}

__global__ __launch_bounds__(256, 3) void mlp_mfma(
    const float* __restrict__ agg, const float* __restrict__ hin,
    const float* __restrict__ b1e, const u16* __restrict__ wt,
    const float* __restrict__ b2, const float* __restrict__ b3,
    float* __restrict__ out)
{
    __shared__ u16 hhi[64 * 128], hlo[64 * 128];
    __shared__ float ssw[4 * 64];
    const int t = threadIdx.x;
    const int wl = t >> 6;
    const int lane = t & 63;
    const int li = lane & 15, g = lane >> 4;
    const int n0 = blockIdx.x * 64;

    const u16* w1hi = wt;
    const u16* w1lo = wt + 16384;
    const u16* w2hi = wt + 32768;
    const u16* w2lo = wt + 49152;
    const u16* w3hi = wt + 65536;
    const u16* w3lo = wt + 73728;

    // ---- stage x = [agg | hidden] into swizzled hi/lo LDS planes ----
#pragma unroll
    for (int i = 0; i < 4; ++i) {
        const int e = i * 2048 + t * 8;
        const int row = e >> 7, col0 = e & 127;
        const int node = min(n0 + row, NN - 1);
        const float* sp = (col0 < 64) ? (agg + (size_t)node * 64 + col0)
                                      : (hin + (size_t)node * 64 + (col0 - 64));
        float4 u0 = *(const float4*)sp;
        float4 u1 = *(const float4*)(sp + 4);
        float f[8] = {u0.x, u0.y, u0.z, u0.w, u1.x, u1.y, u1.z, u1.w};
        s16v8 hv, lv;
#pragma unroll
        for (int j = 0; j < 8; ++j) {
            u16 hb = f2bf(f[j]);
            hv[j] = (short)hb;
            lv[j] = (short)f2bf(f[j] - bf2f(hb));
        }
        const int addr = swz(row, col0 >> 3);
        *(s16v8*)&hhi[addr] = hv;
        *(s16v8*)&hlo[addr] = lv;
    }
    __syncthreads();

    // ================= L1: 128 -> 128 =================
    {
        s16v8 Bh[2][4], Bl[2][4];
#pragma unroll
        for (int c = 0; c < 2; ++c) {
            const int col = (wl * 2 + c) * 16 + li;
#pragma unroll
            for (int ks = 0; ks < 4; ++ks) {
                Bh[c][ks] = *(const s16v8*)(w1hi + col * 128 + ks * 32 + g * 8);
                Bl[c][ks] = *(const s16v8*)(w1lo + col * 128 + ks * 32 + g * 8);
            }
        }
        f32v4 acc[2][4];
#pragma unroll
        for (int c = 0; c < 2; ++c)
#pragma unroll
            for (int rt = 0; rt < 4; ++rt) acc[c][rt] = (f32v4){0.f, 0.f, 0.f, 0.f};
#pragma unroll
        for (int rt = 0; rt < 4; ++rt) {
#pragma unroll
            for (int ks = 0; ks < 4; ++ks) {
                const int addr = swz(rt * 16 + li, ks * 4 + g);
                s16v8 Ah = *(const s16v8*)&hhi[addr];
                s16v8 Al = *(const s16v8*)&hlo[addr];
#pragma unroll
                for (int c = 0; c < 2; ++c) {
                    acc[c][rt] = __builtin_amdgcn_mfma_f32_16x16x32_bf16(Ah, Bh[c][ks], acc[c][rt], 0, 0, 0);
                    acc[c][rt] = __builtin_amdgcn_mfma_f32_16x16x32_bf16(Ah, Bl[c][ks], acc[c][rt], 0, 0, 0);
                    acc[c][rt] = __builtin_amdgcn_mfma_f32_16x16x32_bf16(Al, Bh[c][ks], acc[c][rt], 0, 0, 0);
                }
            }
        }
        __syncthreads();                 // all x reads done -> safe to overwrite
#pragma unroll
        for (int c = 0; c < 2; ++c) {
            const int col = (wl * 2 + c) * 16 + li;
            const float bb = b1e[col];
            const int cbw = col >> 3, c7 = col & 7;
#pragma unroll
            for (int rt = 0; rt < 4; ++rt) {
#pragma unroll
                for (int r = 0; r < 4; ++r) {
                    float hv = fmaxf(acc[c][rt][r] + bb, 0.f);
                    u16 hb = f2bf(hv);
                    u16 lb = f2bf(hv - bf2f(hb));
                    const int row = rt * 16 + g * 4 + r;
                    const int addr = row * 128 + (((cbw ^ (row & 7)) << 3) | c7);
                    hhi[addr] = hb; hlo[addr] = lb;
                }
            }
        }
    }
    __syncthreads();

    // ================= L2: 128 -> 128 =================
    {
        s16v8 Bh[2][4], Bl[2][4];
#pragma unroll
        for (int c = 0; c < 2; ++c) {
            const int col = (wl * 2 + c) * 16 + li;
#pragma unroll
            for (int ks = 0; ks < 4; ++ks) {
                Bh[c][ks] = *(const s16v8*)(w2hi + col * 128 + ks * 32 + g * 8);
                Bl[c][ks] = *(const s16v8*)(w2lo + col * 128 + ks * 32 + g * 8);
            }
        }
        f32v4 acc[2][4];
#pragma unroll
        for (int c = 0; c < 2; ++c)
#pragma unroll
            for (int rt = 0; rt < 4; ++rt) acc[c][rt] = (f32v4){0.f, 0.f, 0.f, 0.f};
#pragma unroll
        for (int rt = 0; rt < 4; ++rt) {
#pragma unroll
            for (int ks = 0; ks < 4; ++ks) {
                const int addr = swz(rt * 16 + li, ks * 4 + g);
                s16v8 Ah = *(const s16v8*)&hhi[addr];
                s16v8 Al = *(const s16v8*)&hlo[addr];
#pragma unroll
                for (int c = 0; c < 2; ++c) {
                    acc[c][rt] = __builtin_amdgcn_mfma_f32_16x16x32_bf16(Ah, Bh[c][ks], acc[c][rt], 0, 0, 0);
                    acc[c][rt] = __builtin_amdgcn_mfma_f32_16x16x32_bf16(Ah, Bl[c][ks], acc[c][rt], 0, 0, 0);
                    acc[c][rt] = __builtin_amdgcn_mfma_f32_16x16x32_bf16(Al, Bh[c][ks], acc[c][rt], 0, 0, 0);
                }
            }
        }
        __syncthreads();
#pragma unroll
        for (int c = 0; c < 2; ++c) {
            const int col = (wl * 2 + c) * 16 + li;
            const float bb = b2[col];
            const int cbw = col >> 3, c7 = col & 7;
#pragma unroll
            for (int rt = 0; rt < 4; ++rt) {
#pragma unroll
                for (int r = 0; r < 4; ++r) {
                    float hv = fmaxf(acc[c][rt][r] + bb, 0.f);
                    u16 hb = f2bf(hv);
                    u16 lb = f2bf(hv - bf2f(hb));
                    const int row = rt * 16 + g * 4 + r;
                    const int addr = row * 128 + (((cbw ^ (row & 7)) << 3) | c7);
                    hhi[addr] = hb; hlo[addr] = lb;
                }
            }
        }
    }
    __syncthreads();

    // ================= L3: 128 -> 64 + row L2 norm =================
    {
        const int col = wl * 16 + li;
        s16v8 Bh[4], Bl[4];
#pragma unroll
        for (int ks = 0; ks < 4; ++ks) {
            Bh[ks] = *(const s16v8*)(w3hi + col * 128 + ks * 32 + g * 8);
            Bl[ks] = *(const s16v8*)(w3lo + col * 128 + ks * 32 + g * 8);
        }
        f32v4 a3[4];
#pragma unroll
        for (int rt = 0; rt < 4; ++rt) a3[rt] = (f32v4){0.f, 0.f, 0.f, 0.f};
#pragma unroll
        for (int rt = 0; rt < 4; ++rt) {
#pragma unroll
            for (int ks = 0; ks < 4; ++ks) {
                const int addr = swz(rt * 16 + li, ks * 4 + g);
                s16v8 Ah = *(const s16v8*)&hhi[addr];
                s16v8 Al = *(const s16v8*)&hlo[addr];
                a3[rt] = __builtin_amdgcn_mfma_f32_16x16x32_bf16(Ah, Bh[ks], a3[rt], 0, 0, 0);
                a3[rt] = __builtin_amdgcn_mfma_f32_16x16x32_bf16(Ah, Bl[ks], a3[rt], 0, 0, 0);
                a3[rt] = __builtin_amdgcn_mfma_f32_16x16x32_bf16(Al, Bh[ks], a3[rt], 0, 0, 0);
            }
        }
        const float bb = b3[col];
        float v[4][4];
#pragma unroll
        for (int rt = 0; rt < 4; ++rt) {
#pragma unroll
            for (int r = 0; r < 4; ++r) {
                float vv = a3[rt][r] + bb;
                v[rt][r] = vv;
                float s2 = vv * vv;
#pragma unroll
                for (int o = 1; o <= 8; o <<= 1) s2 += __shfl_xor(s2, o);
                if (li == 0) ssw[wl * 64 + rt * 16 + g * 4 + r] = s2;
            }
        }
        __syncthreads();
#pragma unroll
        for (int rt = 0; rt < 4; ++rt) {
#pragma unroll
            for (int r = 0; r < 4; ++r) {
                const int row = rt * 16 + g * 4 + r;
                const float tot = ssw[row] + ssw[64 + row] + ssw[128 + row] + ssw[192 + row];
                const float inv = rsqrtf(tot);
                const int node = n0 + row;
                if (node < NN)
                    out[(size_t)node * 64 + col] = v[rt][r] * inv;
            }
        }
    }
}

// -------------------------------------------------------------------------
extern "C" void kernel_launch(void* const* d_in, const int* in_sizes, int n_in,
                              void* d_out, int out_size, void* d_ws, size_t ws_size,
                              hipStream_t stream) {
    const float* hidden = (const float*)d_in[0];
    const int*   src    = (const int*)d_in[1];
    const int*   dst    = (const int*)d_in[2];
    const float* W1f    = (const float*)d_in[3];
    const float* b1f    = (const float*)d_in[4];
    const float* W2f    = (const float*)d_in[5];
    const float* b2f    = (const float*)d_in[6];
    const float* W3f    = (const float*)d_in[7];
    const float* b3f    = (const float*)d_in[8];

    float* agg     = (float*)d_ws;                        // NN*H
    float* b1e     = agg + (size_t)NN * H;                // 128
    float* partial = b1e + 128;                           // 256*64
    float* hA      = partial + 256 * 64;                  // NN*H
    int*   bbase   = (int*)(hA + (size_t)NN * H);         // NB+1
    int*   off     = bbase + (NB + 1);                    // NN+1
    int*   chist   = off + (NN + 1);                      // NCH*NB
    u32*   bin     = (u32*)(chist + NCH * NB);            // NE
    u16*   csr     = (u16*)(bin + NE);                    // NE
    u16*   wt      = (u16*)(((uintptr_t)(csr + NE) + 255) & ~(uintptr_t)255);

    // ---- one-time per call: bucketized CSR + weight planes ----
    hist_kernel<<<NCH, 256, 0, stream>>>(dst, chist);
    cscan_kernel<<<1, 512, 0, stream>>>(chist, bbase);
    scat_kernel<<<NCH, 256, 0, stream>>>(src, dst, chist, bin);
    binB_kernel<<<NB, 256, 0, stream>>>(bin, bbase, off, csr);
    prep_kernel<<<(2 * 40960 + 255) / 256, 256, 0, stream>>>(W1f, W2f, W3f, wt);

    const float* hin = hidden;
    float* houts[4] = { hA, (float*)d_out, hA, (float*)d_out };

    for (int it = 0; it < 4; ++it) {
        const int blk = it >> 1;
        grep_kernel<<<256, 256, 0, stream>>>(hin, partial);
        b1e_kernel<<<1, 128, 0, stream>>>(partial, W1f + blk * 24576, b1f + blk * 128, b1e);
        gather_kernel<<<(NN + 3) / 4, 256, 0, stream>>>(hin, csr, off, agg);
        mlp_mfma<<<(NN + 63) / 64, 256, 0, stream>>>(agg, hin, b1e, wt + blk * 81920,
            b2f + blk * 128, b3f + blk * 64, houts[it]);
        hin = houts[it];
    }
}